// Round 8
// baseline (34.230 us; speedup 1.0000x reference)
//
#include <hip/hip_runtime.h>
#include <hip/hip_bf16.h>

// SemiPool2d max-plus: out[b,c,p,q] = max_{i<7,j<7}( x[b,c,2p+i,2q+j] + w[c,i,j] )
// x: (8,64,224,224) f32, w: (1,64,7,7) f32, out: (8,64,109,109) f32
//
// 4x4 output tile per thread; (b,c) wave-uniform (896 tiles/channel, 64|896)
// so the 49 weights live in SGPRs (readfirstlane + scalar loads).
//  - 4-deep software-pipelined row buffer xr[4][14]: consume row r, then
//    issue loads for row r+4 into the freed slot -> ~3 compute phases
//    between issue and waitcnt, covering L3/HBM latency.
//  - tree-max (nested fmaxf -> v_max3_f32): 7 adds + 4 max per (output,row)
//    instead of a serial 7-deep fmax chain.

#define BB 8
#define CC 64
#define HH 224
#define WW 224
#define HO 109
#define WO 109
#define PT 4
#define QT 4
#define NPB 28   // ceil(109/4)
#define NQB 32   // padded 28->32: 896 tiles per (b,c), multiple of 64
#define DEPTH 4
// total threads = 8*64*28*32 = 458752 = 1792 * 256

__global__ __launch_bounds__(256) void semipool_kernel(
    const float* __restrict__ x,
    const float* __restrict__ w,
    float* __restrict__ out)
{
    int tg = blockIdx.x * 256 + threadIdx.x;

    int qb = tg & 31;          // NQB = 32 (pow2)
    int t  = tg >> 5;
    int pb = t % NPB;
    t = t / NPB;               // t = b*CC + c, wave-uniform by construction

    int q0 = qb * QT; if (q0 > WO - QT) q0 = WO - QT;   // <= 105
    int p0 = pb * PT; if (p0 > HO - PT) p0 = HO - PT;   // <= 105

    int bc = __builtin_amdgcn_readfirstlane(t);

    // 49 channel weights -> SGPRs (uniform address, scalar loads)
    const float* __restrict__ wp = w + (bc & (CC - 1)) * 49;
    float wr[49];
#pragma unroll
    for (int k = 0; k < 49; ++k) wr[k] = wp[k];

    float acc[PT][QT];
#pragma unroll
    for (int a = 0; a < PT; ++a)
#pragma unroll
        for (int d = 0; d < QT; ++d)
            acc[a][d] = -1e30f;

    const float* __restrict__ xbase =
        x + (bc * HH + p0 * 2) * WW + q0 * 2;

    // ---- software pipeline: rows 0..12, DEPTH=4 row buffers ----
    float xr[DEPTH][14];

#pragma unroll
    for (int r = 0; r < DEPTH; ++r) {
#pragma unroll
        for (int k = 0; k < 7; ++k) {
            float2 v = *reinterpret_cast<const float2*>(xbase + r * WW + 2 * k);
            xr[r][2 * k]     = v.x;
            xr[r][2 * k + 1] = v.y;
        }
    }

#pragma unroll
    for (int r = 0; r < 13; ++r) {               // all indices compile-time
        float (&xv)[14] = xr[r & (DEPTH - 1)];

        // consume row r: contributes weight-row i = r - 2*pp to output row pp
#pragma unroll
        for (int pp = 0; pp < PT; ++pp) {
            int i = r - 2 * pp;
            if (i >= 0 && i < 7) {
#pragma unroll
                for (int qq = 0; qq < QT; ++qq) {
                    float s0 = xv[2 * qq + 0] + wr[i * 7 + 0];
                    float s1 = xv[2 * qq + 1] + wr[i * 7 + 1];
                    float s2 = xv[2 * qq + 2] + wr[i * 7 + 2];
                    float s3 = xv[2 * qq + 3] + wr[i * 7 + 3];
                    float s4 = xv[2 * qq + 4] + wr[i * 7 + 4];
                    float s5 = xv[2 * qq + 5] + wr[i * 7 + 5];
                    float s6 = xv[2 * qq + 6] + wr[i * 7 + 6];
                    float t0 = fmaxf(fmaxf(s0, s1), s2);   // v_max3
                    float t1 = fmaxf(fmaxf(s3, s4), s5);   // v_max3
                    float t2 = fmaxf(fmaxf(t0, t1), s6);   // v_max3
                    acc[pp][qq] = fmaxf(acc[pp][qq], t2);
                }
            }
        }

        // prefetch row r+DEPTH into the slot just freed
        if (r + DEPTH < 13) {
#pragma unroll
            for (int k = 0; k < 7; ++k) {
                float2 v = *reinterpret_cast<const float2*>(
                    xbase + (r + DEPTH) * WW + 2 * k);
                xv[2 * k]     = v.x;
                xv[2 * k + 1] = v.y;
            }
        }
    }

#pragma unroll
    for (int pp = 0; pp < PT; ++pp) {
        float* __restrict__ orow = out + (bc * HO + (p0 + pp)) * WO + q0;
#pragma unroll
        for (int qq = 0; qq < QT; ++qq)
            orow[qq] = acc[pp][qq];
    }
}

extern "C" void kernel_launch(void* const* d_in, const int* in_sizes, int n_in,
                              void* d_out, int out_size, void* d_ws, size_t ws_size,
                              hipStream_t stream) {
    const float* x = (const float*)d_in[0];
    const float* w = (const float*)d_in[1];
    float* out = (float*)d_out;

    int total = BB * CC * NPB * NQB;           // 458752
    int blocks = total / 256;                  // 1792
    semipool_kernel<<<blocks, 256, 0, stream>>>(x, w, out);
}

// Round 11
// 27.120 us; speedup vs baseline: 1.2622x; 1.2622x over previous
//
#include <hip/hip_runtime.h>

// SemiPool2d max-plus: out[b,c,p,q] = max_{i<7,j<7}( x[b,c,2p+i,2q+j] + w[c,i,j] )
// x: (8,64,224,224) f32, w: (1,64,7,7) f32, out: (8,64,109,109) f32
//
// Block = one (b*64+c, 16-row output band). Stage the 37x224 input band into
// LDS via global_load_lds (16B chunks, zero-VGPR fire-and-forget DMA -> ~8KB
// in flight per wave, HBM-saturating). Compute: thread = (q, p-half), 8
// outputs per thread in a column; reads 21 LDS rows x 4 ds_read_b64.
// Weights are SGPRs (bc is blockIdx-derived -> scalar loads).

#define HH 224
#define WW 224
#define HO 109
#define WO 109
#define CC 64
#define PBAND 16
#define NB 7                        // ceil(109/16)
#define INROWS (2*PBAND + 5)        // 37
#define LDSF (INROWS*WW)            // 8288 floats = 33152 B
#define CHUNKS (LDSF/4)             // 2072 16B chunks
#define ITERS (CHUNKS/256)          // 8
#define TAIL (CHUNKS - ITERS*256)   // 24

__global__ __launch_bounds__(256) void semipool_kernel(
    const float* __restrict__ x,
    const float* __restrict__ w,
    float* __restrict__ out)
{
    __shared__ float smem[LDSF];

    const int tid  = threadIdx.x;
    const int band = blockIdx.x >> 9;        // 0..6   (grid = 7*512)
    const int bc   = blockIdx.x & 511;       // 0..511 (scalar: SGPR)

    int p0b = band * PBAND;
    if (p0b > HO - PBAND) p0b = HO - PBAND;  // band 6 -> 93
    const int row0 = 2 * p0b;

    // ---- stage 37x224 floats into LDS: linear copy, 16B per lane ----
    const float* src = x + (bc * HH + row0) * WW;
#pragma unroll
    for (int it = 0; it < ITERS; ++it) {
        int c = it * 256 + tid;
        __builtin_amdgcn_global_load_lds(
            (const __attribute__((address_space(1))) void*)(src + 4 * c),
            (__attribute__((address_space(3))) void*)(smem + 4 * c),
            16, 0, 0);
    }
    if (tid < TAIL) {
        int c = ITERS * 256 + tid;
        __builtin_amdgcn_global_load_lds(
            (const __attribute__((address_space(1))) void*)(src + 4 * c),
            (__attribute__((address_space(3))) void*)(smem + 4 * c),
            16, 0, 0);
    }

    // 49 channel weights -> SGPRs (uniform address: bc from blockIdx)
    const float* __restrict__ wp = w + (bc & (CC - 1)) * 49;
    float wr[49];
#pragma unroll
    for (int k = 0; k < 49; ++k) wr[k] = wp[k];

    __syncthreads();   // drains vmcnt(0) -> LDS fully populated

    // ---- compute: thread = (q, p-half); 8 outputs in a column ----
    int q = tid & 127; if (q > WO - 1) q = WO - 1;   // 0..108 (dups benign)
    const int ph   = tid >> 7;                      // 0 or 1
    const int p0t  = p0b + 8 * ph;                  // output rows p0t..p0t+7
    const int colb = 2 * q;                         // <= 216, even

    float acc[8];
#pragma unroll
    for (int a = 0; a < 8; ++a) acc[a] = -1e30f;

#pragma unroll
    for (int r = 0; r < 21; ++r) {                  // rel input rows
        const float* lr = smem + (16 * ph + r) * WW + colb;
        float xr[8];
#pragma unroll
        for (int k = 0; k < 4; ++k) {
            float2 v = *reinterpret_cast<const float2*>(lr + 2 * k);
            xr[2 * k]     = v.x;
            xr[2 * k + 1] = v.y;
        }
#pragma unroll
        for (int pp = 0; pp < 8; ++pp) {
            int i = r - 2 * pp;                     // compile-time after unroll
            if (i >= 0 && i < 7) {
                float s0 = xr[0] + wr[i * 7 + 0];
                float s1 = xr[1] + wr[i * 7 + 1];
                float s2 = xr[2] + wr[i * 7 + 2];
                float s3 = xr[3] + wr[i * 7 + 3];
                float s4 = xr[4] + wr[i * 7 + 4];
                float s5 = xr[5] + wr[i * 7 + 5];
                float s6 = xr[6] + wr[i * 7 + 6];
                float t0 = fmaxf(fmaxf(s0, s1), s2);   // v_max3
                float t1 = fmaxf(fmaxf(s3, s4), s5);   // v_max3
                float t2 = fmaxf(fmaxf(t0, t1), s6);   // v_max3
                acc[pp] = fmaxf(acc[pp], t2);
            }
        }
    }

    // ---- store: 8 scalar stores, lanes contiguous in q -> coalesced ----
    float* __restrict__ orow = out + (bc * HO + p0t) * WO + q;
#pragma unroll
    for (int pp = 0; pp < 8; ++pp)
        orow[pp * WO] = acc[pp];
}

extern "C" void kernel_launch(void* const* d_in, const int* in_sizes, int n_in,
                              void* d_out, int out_size, void* d_ws, size_t ws_size,
                              hipStream_t stream) {
    const float* x = (const float*)d_in[0];
    const float* w = (const float*)d_in[1];
    float* out = (float*)d_out;

    int blocks = NB * 512;                     // 3584
    semipool_kernel<<<blocks, 256, 0, stream>>>(x, w, out);
}